// Round 2
// baseline (888.606 us; speedup 1.0000x reference)
//
#include <hip/hip_runtime.h>
#include <hip/hip_bf16.h>

#define XY 65160     // 360*181
#define NI 96
#define NO 96
#define NK 8
#define NTILE 1019   // ceil(XY/64)

typedef __attribute__((ext_vector_type(8))) short short8;
typedef __attribute__((ext_vector_type(4))) float floatx4;

union FragU { short8 v; unsigned u[4]; };

static __device__ __forceinline__ unsigned bf16r(float x) {
    unsigned u = __builtin_bit_cast(unsigned, x);
    return (u + 0x7FFFu + ((u >> 16) & 1u)) >> 16;   // round-to-nearest-even
}
static __device__ __forceinline__ unsigned pk_bf16(float lo, float hi) {
    return bf16r(lo) | (bf16r(hi) << 16);
}

__global__ __launch_bounds__(256) void cmult_kernel(
    const float* __restrict__ inp, const float* __restrict__ weight,
    const float* __restrict__ bias, float* __restrict__ out)
{
    // packed bf16 (wr,wi) pairs, stored in MFMA A-fragment order: 36 KB
    __shared__ unsigned wlds[36 * 64 * 4];

    const int tid  = threadIdx.x;
    const int lane = tid & 63;
    const int wave = tid >> 6;
    const int k    = blockIdx.y;
    const int l15  = lane & 15;
    const int quad = lane >> 4;

    const float* wk   = weight + (size_t)k * NI * NO * 2;
    const float* inpk = inp    + (size_t)k * NI * XY * 2;

    // ---- stage weight (fp32 -> packed bf16 pair) into A-fragment layout ----
    // fragment (s,m): lane holds o = 16m + (lane&15), kk = 32s + (lane>>4)*8 + j
    // kk = 2i + c  ->  i = 16s + 4*(lane>>4) + t,  u[t] = (bf16(wr) | bf16(wi)<<16)
    for (int idx = tid; idx < NI * NO; idx += 256) {
        int i = idx / NO;
        int o = idx - i * NO;
        float2 w = *reinterpret_cast<const float2*>(wk + (size_t)idx * 2);
        int s = i >> 4, q = (i >> 2) & 3, t = i & 3;
        int m = o >> 4, c = o & 15;
        wlds[((s * 6 + m) * 64 + (q * 16 + c)) * 4 + t] = pk_bf16(w.x, w.y);
    }
    __syncthreads();

    // ---- grid-stride loop over 64-xy tiles (16 xy per wave) ----
    for (int tidx = blockIdx.x; tidx < NTILE; tidx += gridDim.x) {
        int xy  = tidx * 64 + wave * 16 + l15;
        int xyc = xy < XY ? xy : XY - 1;   // clamp loads; stores predicated

        floatx4 accR[6], accI[6];
        #pragma unroll
        for (int m = 0; m < 6; ++m) {
            accR[m] = (floatx4){0.f, 0.f, 0.f, 0.f};
            accI[m] = (floatx4){0.f, 0.f, 0.f, 0.f};
        }

        #pragma unroll
        for (int s = 0; s < 6; ++s) {
            // input B-fragment: B[kk][xy], kk = 32s + quad*8 + j; read-once from global
            FragU bfr;
            #pragma unroll
            for (int t = 0; t < 4; ++t) {
                int i = 16 * s + 4 * quad + t;
                float2 a = *reinterpret_cast<const float2*>(inpk + ((size_t)i * XY + xyc) * 2);
                bfr.u[t] = pk_bf16(a.x, a.y);   // (real, imag) -> (kk even, kk odd)
            }
            #pragma unroll
            for (int m = 0; m < 6; ++m) {
                uint4 wp = *(reinterpret_cast<const uint4*>(wlds) + (s * 6 + m) * 64 + lane);
                unsigned pw[4] = {wp.x, wp.y, wp.z, wp.w};
                FragU w0, w1;
                #pragma unroll
                for (int t = 0; t < 4; ++t) {
                    w0.u[t] = pw[t] ^ 0x80000000u;             // (wr, -wi) -> real chain
                    w1.u[t] = (pw[t] >> 16) | (pw[t] << 16);   // (wi,  wr) -> imag chain
                }
                accR[m] = __builtin_amdgcn_mfma_f32_16x16x32_bf16(w0.v, bfr.v, accR[m], 0, 0, 0);
                accI[m] = __builtin_amdgcn_mfma_f32_16x16x32_bf16(w1.v, bfr.v, accI[m], 0, 0, 0);
            }
        }

        // ---- epilogue: D col = lane&15 (xy), row = quad*4 + r (o within 16-tile) ----
        if (xy < XY) {
            #pragma unroll
            for (int m = 0; m < 6; ++m) {
                #pragma unroll
                for (int r = 0; r < 4; ++r) {
                    int o = 16 * m + 4 * quad + r;
                    float2 b = *reinterpret_cast<const float2*>(bias + ((size_t)k * NO + o) * 2);
                    float2 ov;
                    ov.x = accR[m][r] + b.x;
                    ov.y = accI[m][r] + b.y;
                    *reinterpret_cast<float2*>(out + ((size_t)(k * NO + o) * XY + xy) * 2) = ov;
                }
            }
        }
    }
}

extern "C" void kernel_launch(void* const* d_in, const int* in_sizes, int n_in,
                              void* d_out, int out_size, void* d_ws, size_t ws_size,
                              hipStream_t stream)
{
    const float* inp    = (const float*)d_in[0];
    const float* weight = (const float*)d_in[1];
    const float* bias   = (const float*)d_in[2];
    float* out = (float*)d_out;

    dim3 grid(128, NK), block(256);
    hipLaunchKernelGGL(cmult_kernel, grid, block, 0, stream, inp, weight, bias, out);
}